// Round 7
// baseline (149.670 us; speedup 1.0000x reference)
//
#include <hip/hip_runtime.h>
#include <hip/hip_bf16.h>

typedef _Float16 f16_8 __attribute__((ext_vector_type(8)));
typedef _Float16 f16_4 __attribute__((ext_vector_type(4)));
typedef float f32x4 __attribute__((ext_vector_type(4)));

#define NNODES 113
#define NGRAPH 4096

// ---------------- ws layout (bytes), empirically-safe envelope [0, 11,608,064)
// All regions disjoint. Old z fp32 region [0, 2 MB) now holds zh fp16 + w3p.
#define ZH_OFF   0u            // 4096*128*2 = 1,048,576 (fp16)  [k1 -> k2]
#define W3P_OFF  1048576u      // 65536*2 = 131,072 fp16         [k0 -> k2]
#define PH_OFF   2097152u      // 4096*512*2 = 4,194,304 (fp16)  [k2 -> k4]
#define PSUM_OFF 6291456u      // 256*512*4 = 524,288            [k2 -> k3]
#define PSQ_OFF  6815744u      // 256*512*4 = 524,288            [k2 -> k3]
#define GC_OFF   10485760u     // 128*4                          [k0 -> k1]
#define SA_OFF   10489856u     // 512*4                          [k3 -> k4]
#define SD_OFF   10491904u     // 512*4                          [k3 -> k4]
#define W2P_OFF  10493952u     // 16384*2 fp16                   [k0 -> k1]
#define W4P_OFF  10559488u     // 524288*2 fp16 -> end 11,608,064 [k0 -> k4]

// K0: blocks 0..255: W4 -> fp16 B-frag pack via LDS transpose;
// 256..263: W2 pack; 264: GN quadform consts; 265..296: W3 pack.
// B-frag: elem ((kt*NT+nt)*64+L)*8+j <= W[k][n], k=kt*32+(L>>4)*8+j, n=nt*16+(L&15)
__global__ __launch_bounds__(256) void k0_prep(
    const float* __restrict__ W2, const float* __restrict__ W4,
    const float* __restrict__ W1, const float* __restrict__ b1,
    const float* __restrict__ W3,
    _Float16* __restrict__ w2p, _Float16* __restrict__ w4p,
    _Float16* __restrict__ w3p, float* __restrict__ gc) {
  int b = blockIdx.x, t = threadIdx.x;
  if (b < 256) {                    // W4 tile: 32 k-rows x 64 n-cols
    __shared__ _Float16 T[32 * 72];
    int kt = b >> 4, nc = b & 15;
    int row = t >> 3, c8 = (t & 7) * 8;
    const float* src = &W4[(kt * 32 + row) * 1024 + nc * 64 + c8];
    float4 a0 = *(const float4*)src;
    float4 a1 = *(const float4*)(src + 4);
    f16_8 v = {(_Float16)a0.x, (_Float16)a0.y, (_Float16)a0.z, (_Float16)a0.w,
               (_Float16)a1.x, (_Float16)a1.y, (_Float16)a1.z, (_Float16)a1.w};
    *(f16_8*)&T[row * 72 + c8] = v;
    __syncthreads();
    int ntl = t >> 6, L = t & 63;
    f16_8 w;
#pragma unroll
    for (int j = 0; j < 8; j++)
      w[j] = T[((L >> 4) * 8 + j) * 72 + ntl * 16 + (L & 15)];
    *(f16_8*)&w4p[((kt * 64 + nc * 4 + ntl) * 64 + L) * 8] = w;
  } else if (b < 264) {             // W2 pack
    int q0 = (b - 256) * 256 + t;
    int L = q0 & 63, nt = (q0 >> 6) & 7, kt = q0 >> 9;
    f16_8 v;
#pragma unroll
    for (int j = 0; j < 8; j++)
      v[j] = (_Float16)W2[(kt * 32 + ((L >> 4) << 3) + j) * 128 + (nt << 4) + (L & 15)];
    *(f16_8*)&w2p[((kt * 8 + nt) * 64 + L) * 8] = v;
  } else if (b == 264) {            // GN quadform consts
    if (t < 128) {
      float a0 = W1[t], a1 = W1[128 + t], a2 = W1[256 + t], bb = b1[t];
      float p[14] = {a0, a1, a2, bb,
                     a0 * a0, 2.f * a0 * a1, 2.f * a0 * a2,
                     a1 * a1, 2.f * a1 * a2, a2 * a2,
                     2.f * bb * a0, 2.f * bb * a1, 2.f * bb * a2, bb * bb};
#pragma unroll
      for (int m = 1; m < 16; m <<= 1)
#pragma unroll
        for (int k = 0; k < 14; k++) p[k] += __shfl_xor(p[k], m, 64);
      if ((t & 15) == 0) {
        int gg = t >> 4;
#pragma unroll
        for (int k = 0; k < 4; k++) gc[gg * 16 + k] = p[k] * 0.0625f;
#pragma unroll
        for (int k = 4; k < 14; k++) gc[gg * 16 + k] = p[k];
      }
    }
  } else {                          // W3 pack: 4kt x 32nt x 64L
    int q1 = (b - 265) * 256 + t;
    int L = q1 & 63, nt = (q1 >> 6) & 31, kt = q1 >> 11;
    f16_8 v;
#pragma unroll
    for (int j = 0; j < 8; j++)
      v[j] = (_Float16)W3[(kt * 32 + ((L >> 4) << 3) + j) * 512 + (nt << 4) + (L & 15)];
    *(f16_8*)&w3p[((kt * 32 + nt) * 64 + L) * 8] = v;
  }
}

// K1: per-graph node net + max pool. Stats merged into fill (octet's 8 channels
// share one GN group -> inline fp32 quadform), 2 barriers, fp16 MFMA.
// Output zh is fp16 (same rounding as k2 would apply; halves k1->k2 traffic).
// NOTE (R5 post-mortem): 4-graphs/block variant spilled to scratch
// (VGPR_Count 64, ~800 MB scratch traffic, 200 µs) — keep 1 graph/block.
// R7: A-tile stored LINEAR pitch 128 f16 (256 B) with XOR swizzle
// byte ^= ((row&7)<<4) — writes are 4 contiguous 256-B rows (conflict-free),
// reads become 2-way (free); replaces pitch-136 pad (2.1M bank-conflict
// cycles/dispatch measured). Pure slot permutation -> bit-identical output.
__global__ __launch_bounds__(256, 4) void k1_nodenet(
    const float* __restrict__ x, const float* __restrict__ roi,
    const float* __restrict__ W1, const float* __restrict__ b1,
    const float* __restrict__ gn_g, const float* __restrict__ gn_b,
    const _Float16* __restrict__ w2p, const float* __restrict__ b2,
    const float* __restrict__ gc, _Float16* __restrict__ zh) {
  __shared__ float4 xs4[NNODES];
  __shared__ _Float16 A[128 * 128];   // linear 256 B/row + XOR swizzle
  int t = threadIdx.x, g = blockIdx.x;
  int lane = t & 63, wv = t >> 6, quad = lane >> 4, l16 = lane & 15;

  int o = t & 15;
  int gq = o >> 1;
  float gcv[14];
#pragma unroll
  for (int j = 0; j < 14; j++) gcv[j] = gc[gq * 16 + j];

  float pw0[8], pw1[8], pw2[8], pb[8], pg[8], pbe[8];
#pragma unroll
  for (int j = 0; j < 8; j++) {
    int c = o * 8 + j;
    pw0[j] = W1[c]; pw1[j] = W1[128 + c]; pw2[j] = W1[256 + c];
    pb[j] = b1[c];  pg[j] = gn_g[c];      pbe[j] = gn_b[c];
  }

  f16_8 bh[4][2];
#pragma unroll
  for (int kt = 0; kt < 4; kt++)
#pragma unroll
    for (int ni = 0; ni < 2; ni++)
      bh[kt][ni] = *(const f16_8*)&w2p[((kt * 8 + wv * 2 + ni) * 64 + lane) * 8];

  for (int i = t; i < NNODES * 3; i += 256) {
    float v = x[g * (NNODES * 3) + i] * roi[i];
    ((float*)xs4)[(i / 3) * 4 + (i % 3)] = v;
  }
  __syncthreads();

  for (int it = t; it < 2048; it += 256) {
    int n = it >> 4;
    f16_8 hv;
    if (n < NNODES) {
      float4 xv = xs4[n];
      float mu = fmaf(xv.z, gcv[2], fmaf(xv.y, gcv[1], fmaf(xv.x, gcv[0], gcv[3])));
      float qf = fmaf(xv.z, gcv[12], fmaf(xv.y, gcv[11], fmaf(xv.x, gcv[10], gcv[13])));
      float u0 = fmaf(xv.z, gcv[6], fmaf(xv.y, gcv[5], xv.x * gcv[4]));
      qf = fmaf(xv.x, u0, qf);
      float u1 = fmaf(xv.z, gcv[8], xv.y * gcv[7]);
      qf = fmaf(xv.y, u1, qf);
      qf = fmaf(xv.z * xv.z, gcv[9], qf);
      float var = fmaxf(qf * 0.0625f - mu * mu, 0.0f);
      float ia = rsqrtf(var + 1e-5f);
      float ib = -mu * ia;
#pragma unroll
      for (int j = 0; j < 8; j++) {
        float h = fmaf(xv.z, pw2[j], fmaf(xv.y, pw1[j], fmaf(xv.x, pw0[j], pb[j])));
        float y = fmaf(fmaf(h, ia, ib), pg[j], pbe[j]);
        y = (y > 0.0f) ? y : 0.2f * y;
        hv[j] = (_Float16)y;
      }
    } else {
#pragma unroll
      for (int j = 0; j < 8; j++) hv[j] = (_Float16)0.f;
    }
    // swizzled store: row n, 16-B slot o, slot ^= (n&7)
    *(f16_8*)((char*)A + n * 256 + ((o * 16) ^ ((n & 7) << 4))) = hv;
  }
  __syncthreads();

  f32x4 acc[2][8];
#pragma unroll
  for (int a = 0; a < 2; a++)
#pragma unroll
    for (int m = 0; m < 8; m++) acc[a][m] = (f32x4){0.f, 0.f, 0.f, 0.f};

  int sx = (l16 & 7) << 4;   // (row&7)<<4 for row = mt*16 + l16
#pragma unroll
  for (int kt = 0; kt < 4; kt++) {
    f16_8 ah[8];
#pragma unroll
    for (int mt = 0; mt < 8; mt++)
      ah[mt] = *(const f16_8*)((const char*)A + (mt * 16 + l16) * 256 +
                               ((kt * 64 + quad * 16) ^ sx));
#pragma unroll
    for (int ni = 0; ni < 2; ni++)
#pragma unroll
      for (int mt = 0; mt < 8; mt++)
        acc[ni][mt] = __builtin_amdgcn_mfma_f32_16x16x32_f16(ah[mt], bh[kt][ni], acc[ni][mt], 0, 0, 0);
  }

#pragma unroll
  for (int ni = 0; ni < 2; ni++) {
    int nt = wv * 2 + ni;
    float m = -3.4e38f;
#pragma unroll
    for (int mt = 0; mt < 8; mt++)
#pragma unroll
      for (int r = 0; r < 4; r++) {
        int row = mt * 16 + quad * 4 + r;
        if (row < NNODES) m = fmaxf(m, acc[ni][mt][r]);
      }
    m = fmaxf(m, __shfl_xor(m, 16, 64));
    m = fmaxf(m, __shfl_xor(m, 32, 64));
    if (quad == 0) {
      int col = nt * 16 + l16;
      zh[g * 128 + col] = (_Float16)(m + b2[col]);
    }
  }
}

// K2: p = zh @ W3 + b3 via MFMA -> fp16 ph; fused deterministic BN partials.
// 512 blocks = 256 row-blocks x 2 col-halves; block = 16 rows x 256 cols,
// 4 waves, wave owns 64 cols (4 ni). A-frags loaded DIRECTLY from global zh
// (1 MB, L2-resident; no LDS staging). 16 MFMA/wave. Partials: fixed r-loop +
// fixed xor-16/32 tree -> deterministic; psum layout unchanged (k3 untouched).
__global__ __launch_bounds__(256) void k2_proj(
    const _Float16* __restrict__ zh, const _Float16* __restrict__ w3p,
    const float* __restrict__ b3, _Float16* __restrict__ ph,
    float* __restrict__ psum, float* __restrict__ psq) {
  int t = threadIdx.x;
  int rb = blockIdx.x >> 1, cb = blockIdx.x & 1;
  int lane = t & 63, w = t >> 6, quad = lane >> 4, l16 = lane & 15;

  f16_8 bf[4][4];
#pragma unroll
  for (int kt = 0; kt < 4; kt++)
#pragma unroll
    for (int ni = 0; ni < 4; ni++)
      bf[kt][ni] = *(const f16_8*)&w3p[((kt * 32 + cb * 16 + w * 4 + ni) * 64 + lane) * 8];

  const _Float16* za = &zh[(rb * 16 + l16) * 128 + quad * 8];
  f32x4 acc[4];
#pragma unroll
  for (int ni = 0; ni < 4; ni++) acc[ni] = (f32x4){0.f, 0.f, 0.f, 0.f};
#pragma unroll
  for (int kt = 0; kt < 4; kt++) {
    f16_8 af = *(const f16_8*)&za[kt * 32];
#pragma unroll
    for (int ni = 0; ni < 4; ni++)
      acc[ni] = __builtin_amdgcn_mfma_f32_16x16x32_f16(af, bf[kt][ni], acc[ni], 0, 0, 0);
  }

#pragma unroll
  for (int ni = 0; ni < 4; ni++) {
    int col = cb * 256 + w * 64 + ni * 16 + l16;
    float bv = b3[col];
    float sx = 0.f, qx = 0.f;
#pragma unroll
    for (int r = 0; r < 4; r++) {
      float v = acc[ni][r] + bv;
      ph[(rb * 16 + quad * 4 + r) * 512 + col] = (_Float16)v;
      sx += v;
      qx = fmaf(v, v, qx);
    }
    sx += __shfl_xor(sx, 16, 64);
    sx += __shfl_xor(sx, 32, 64);
    qx += __shfl_xor(qx, 16, 64);
    qx += __shfl_xor(qx, 32, 64);
    if (quad == 0) {
      psum[rb * 512 + col] = sx;
      psq[rb * 512 + col] = qx;
    }
  }
}

// K3: parallel reduce of 256 partials -> BN scale a, shift d.
// 64 blocks x 8 cols; 32 lanes/col each summing 8 partials, butterfly combine.
// Fixed partition + fixed tree order -> deterministic.
__global__ __launch_bounds__(256) void k3_stats(
    const float* __restrict__ psum, const float* __restrict__ psq,
    const float* __restrict__ bn_g, const float* __restrict__ bn_b,
    float* __restrict__ sa, float* __restrict__ sd) {
  int t = threadIdx.x;
  int c = blockIdx.x * 8 + (t >> 5);
  int l = t & 31;
  float s = 0.f, q = 0.f;
#pragma unroll
  for (int i = 0; i < 8; i++) {
    int b = l + i * 32;
    s += psum[b * 512 + c];
    q += psq[b * 512 + c];
  }
#pragma unroll
  for (int m = 1; m < 32; m <<= 1) {
    s += __shfl_xor(s, m, 64);
    q += __shfl_xor(q, m, 64);
  }
  if (l == 0) {
    float mu = s * (1.0f / 4096.0f);
    float var = fmaxf(q * (1.0f / 4096.0f) - mu * mu, 0.0f);
    float sc = bn_g[c] * rsqrtf(var + 1e-5f);
    sa[c] = sc;
    sd[c] = bn_b[c] - mu * sc;
  }
}

// K4: fused p@W4 + b4 + L2-normalize. 128 blocks x 32 rows x FULL 1024 cols
// (512 threads; wave w owns cols [128w,128w+128), 2 row-tiles). A =
// relu(ph*sa+sd) staged once in LDS ([kt][32 rows][40] fp16 = 40 KB), K-loop
// has ZERO barriers: B streamed from L2 via double-buffered register prefetch
// (static indices). Row sumsq reduced in-reg + LDS; out written once,
// normalized. Fixed reduce order -> deterministic.
__global__ __launch_bounds__(512) void k4_gemm(
    const _Float16* __restrict__ ph, const float* __restrict__ sa,
    const float* __restrict__ sd, const _Float16* __restrict__ w4p,
    const float* __restrict__ b4, float* __restrict__ out) {
  __shared__ _Float16 A[16 * 32 * 40];   // [kt][row(32)][40] : 40 KB
  __shared__ float sas[512], sds[512];
  __shared__ float rowsq[8][32];
  __shared__ float rinv[32];
  int t = threadIdx.x;
  int rb = blockIdx.x;                   // 32 rows per block
  int lane = t & 63, w = t >> 6, quad = lane >> 4, l16 = lane & 15;

  sas[t] = sa[t];
  sds[t] = sd[t];

  // stage loads: 32 rows x 64 f16_8-segs = 2048 slots, 4 per thread, coalesced
  f16_8 pv[4];
#pragma unroll
  for (int p = 0; p < 4; p++) {
    int idx = t + p * 512;
    int row = idx >> 6, seg = idx & 63;
    pv[p] = *(const f16_8*)&ph[(rb * 32 + row) * 512 + seg * 8];
  }
  int nt0 = w * 8;
  f16_8 bf0[8], bf1[8];
#pragma unroll
  for (int ni = 0; ni < 8; ni++)
    bf0[ni] = *(const f16_8*)&w4p[((nt0 + ni) * 64 + lane) * 8];
  __syncthreads();   // sas/sds ready

#pragma unroll
  for (int p = 0; p < 4; p++) {
    int idx = t + p * 512;
    int row = idx >> 6, seg = idx & 63;
    int kt = seg >> 2, c8 = seg & 3;
    f16_8 v;
#pragma unroll
    for (int j = 0; j < 8; j++) {
      float vv = fmaf((float)pv[p][j], sas[seg * 8 + j], sds[seg * 8 + j]);
      v[j] = (_Float16)fmaxf(vv, 0.f);
    }
    *(f16_8*)&A[(kt * 32 + row) * 40 + c8 * 8] = v;
  }
  __syncthreads();   // A ready; no more barriers until epilogue

  f32x4 acc[2][8];
#pragma unroll
  for (int mt = 0; mt < 2; mt++)
#pragma unroll
    for (int ni = 0; ni < 8; ni++) acc[mt][ni] = (f32x4){0.f, 0.f, 0.f, 0.f};

#pragma unroll
  for (int kt2 = 0; kt2 < 8; kt2++) {
    const int ktA = kt2 * 2, ktB = kt2 * 2 + 1;
#pragma unroll
    for (int ni = 0; ni < 8; ni++)
      bf1[ni] = *(const f16_8*)&w4p[(((ktA + 1) * 64 + nt0 + ni) * 64 + lane) * 8];
    f16_8 afA0 = *(const f16_8*)&A[(ktA * 32 + l16) * 40 + quad * 8];
    f16_8 afA1 = *(const f16_8*)&A[(ktA * 32 + 16 + l16) * 40 + quad * 8];
#pragma unroll
    for (int ni = 0; ni < 8; ni++)
      acc[0][ni] = __builtin_amdgcn_mfma_f32_16x16x32_f16(afA0, bf0[ni], acc[0][ni], 0, 0, 0);
#pragma unroll
    for (int ni = 0; ni < 8; ni++)
      acc[1][ni] = __builtin_amdgcn_mfma_f32_16x16x32_f16(afA1, bf0[ni], acc[1][ni], 0, 0, 0);
    if (kt2 < 7) {
#pragma unroll
      for (int ni = 0; ni < 8; ni++)
        bf0[ni] = *(const f16_8*)&w4p[(((ktB + 1) * 64 + nt0 + ni) * 64 + lane) * 8];
    }
    f16_8 afB0 = *(const f16_8*)&A[(ktB * 32 + l16) * 40 + quad * 8];
    f16_8 afB1 = *(const f16_8*)&A[(ktB * 32 + 16 + l16) * 40 + quad * 8];
#pragma unroll
    for (int ni = 0; ni < 8; ni++)
      acc[0][ni] = __builtin_amdgcn_mfma_f32_16x16x32_f16(afB0, bf1[ni], acc[0][ni], 0, 0, 0);
#pragma unroll
    for (int ni = 0; ni < 8; ni++)
      acc[1][ni] = __builtin_amdgcn_mfma_f32_16x16x32_f16(afB1, bf1[ni], acc[1][ni], 0, 0, 0);
  }

  // epilogue: +b4, row sumsq for 32 rows (rows mt*16+quad*4+r), wave-local
  // reduce over l16, then cross-wave fixed-order sum in LDS.
  float rsq[2][4];
#pragma unroll
  for (int mt = 0; mt < 2; mt++)
#pragma unroll
    for (int r = 0; r < 4; r++) rsq[mt][r] = 0.f;
#pragma unroll
  for (int ni = 0; ni < 8; ni++) {
    float bv = b4[w * 128 + ni * 16 + l16];
#pragma unroll
    for (int mt = 0; mt < 2; mt++)
#pragma unroll
      for (int r = 0; r < 4; r++) {
        float v = acc[mt][ni][r] + bv;
        acc[mt][ni][r] = v;
        rsq[mt][r] = fmaf(v, v, rsq[mt][r]);
      }
  }
#pragma unroll
  for (int m = 1; m < 16; m <<= 1)
#pragma unroll
    for (int mt = 0; mt < 2; mt++)
#pragma unroll
      for (int r = 0; r < 4; r++) rsq[mt][r] += __shfl_xor(rsq[mt][r], m, 64);
  if (l16 == 0)
#pragma unroll
    for (int mt = 0; mt < 2; mt++)
#pragma unroll
      for (int r = 0; r < 4; r++)
        rowsq[w][mt * 16 + quad * 4 + r] = rsq[mt][r];
  __syncthreads();
  if (t < 32) {
    float s = 0.f;
#pragma unroll
    for (int ww = 0; ww < 8; ww++) s += rowsq[ww][t];   // fixed order
    rinv[t] = 1.0f / fmaxf(sqrtf(s), 1e-12f);
  }
  __syncthreads();
#pragma unroll
  for (int mt = 0; mt < 2; mt++)
#pragma unroll
    for (int r = 0; r < 4; r++) {
      float inv = rinv[mt * 16 + quad * 4 + r];
      int obase = (rb * 32 + mt * 16 + quad * 4 + r) * 1024 + w * 128 + l16;
#pragma unroll
      for (int ni = 0; ni < 8; ni++)
        out[obase + ni * 16] = acc[mt][ni][r] * inv;
    }
}

extern "C" void kernel_launch(void* const* d_in, const int* in_sizes, int n_in,
                              void* d_out, int out_size, void* d_ws, size_t ws_size,
                              hipStream_t stream) {
  const float* x   = (const float*)d_in[0];
  const float* roi = (const float*)d_in[1];
  const float* W1  = (const float*)d_in[2];
  const float* b1  = (const float*)d_in[3];
  const float* gng = (const float*)d_in[4];
  const float* gnb = (const float*)d_in[5];
  const float* W2  = (const float*)d_in[6];
  const float* b2  = (const float*)d_in[7];
  const float* W3  = (const float*)d_in[8];
  const float* b3  = (const float*)d_in[9];
  const float* bng = (const float*)d_in[10];
  const float* bnb = (const float*)d_in[11];
  const float* W4  = (const float*)d_in[12];
  const float* b4  = (const float*)d_in[13];
  float* out = (float*)d_out;

  char* ws = (char*)d_ws;
  _Float16* zh   = (_Float16*)(ws + ZH_OFF);
  _Float16* w3p  = (_Float16*)(ws + W3P_OFF);
  _Float16* ph   = (_Float16*)(ws + PH_OFF);
  float*    psum = (float*)(ws + PSUM_OFF);
  float*    psq  = (float*)(ws + PSQ_OFF);
  float*    gc   = (float*)(ws + GC_OFF);
  float*    sa   = (float*)(ws + SA_OFF);
  float*    sd   = (float*)(ws + SD_OFF);
  _Float16* w2p  = (_Float16*)(ws + W2P_OFF);
  _Float16* w4p  = (_Float16*)(ws + W4P_OFF);

  k0_prep<<<297, 256, 0, stream>>>(W2, W4, W1, b1, W3, w2p, w4p, w3p, gc);
  k1_nodenet<<<NGRAPH, 256, 0, stream>>>(x, roi, W1, b1, gng, gnb, w2p, b2, gc, zh);
  k2_proj<<<512, 256, 0, stream>>>(zh, w3p, b3, ph, psum, psq);
  k3_stats<<<64, 256, 0, stream>>>(psum, psq, bng, bnb, sa, sd);
  k4_gemm<<<128, 512, 0, stream>>>(ph, sa, sd, w4p, b4, out);
}

// Round 8
// 145.245 us; speedup vs baseline: 1.0305x; 1.0305x over previous
//
#include <hip/hip_runtime.h>
#include <hip/hip_bf16.h>

typedef _Float16 f16_8 __attribute__((ext_vector_type(8)));
typedef _Float16 f16_4 __attribute__((ext_vector_type(4)));
typedef _Float16 f16_2 __attribute__((ext_vector_type(2)));
typedef float f32x4 __attribute__((ext_vector_type(4)));

#define NNODES 113
#define NGRAPH 4096

// ---------------- ws layout (bytes), empirically-safe envelope [0, 11,608,064)
// All regions disjoint. Old z fp32 region [0, 2 MB) now holds zh fp16 + w3p.
#define ZH_OFF   0u            // 4096*128*2 = 1,048,576 (fp16)  [k1 -> k2]
#define W3P_OFF  1048576u      // 65536*2 = 131,072 fp16         [k0 -> k2]
#define PH_OFF   2097152u      // 4096*512*2 = 4,194,304 (fp16)  [k2 -> k4]
#define PSUM_OFF 6291456u      // 256*512*4 = 524,288            [k2 -> k3]
#define PSQ_OFF  6815744u      // 256*512*4 = 524,288            [k2 -> k3]
#define GC_OFF   10485760u     // 128*4                          [k0 -> k1]
#define SA_OFF   10489856u     // 512*4                          [k3 -> k4]
#define SD_OFF   10491904u     // 512*4                          [k3 -> k4]
#define W2P_OFF  10493952u     // 16384*2 fp16                   [k0 -> k1]
#define W4P_OFF  10559488u     // 524288*2 fp16 -> end 11,608,064 [k0 -> k4]

// K0: blocks 0..255: W4 -> fp16 B-frag pack via LDS transpose;
// 256..263: W2 pack; 264: GN quadform consts; 265..296: W3 pack.
// B-frag: elem ((kt*NT+nt)*64+L)*8+j <= W[k][n], k=kt*32+(L>>4)*8+j, n=nt*16+(L&15)
__global__ __launch_bounds__(256) void k0_prep(
    const float* __restrict__ W2, const float* __restrict__ W4,
    const float* __restrict__ W1, const float* __restrict__ b1,
    const float* __restrict__ W3,
    _Float16* __restrict__ w2p, _Float16* __restrict__ w4p,
    _Float16* __restrict__ w3p, float* __restrict__ gc) {
  int b = blockIdx.x, t = threadIdx.x;
  if (b < 256) {                    // W4 tile: 32 k-rows x 64 n-cols
    __shared__ _Float16 T[32 * 72];
    int kt = b >> 4, nc = b & 15;
    int row = t >> 3, c8 = (t & 7) * 8;
    const float* src = &W4[(kt * 32 + row) * 1024 + nc * 64 + c8];
    float4 a0 = *(const float4*)src;
    float4 a1 = *(const float4*)(src + 4);
    f16_8 v = {(_Float16)a0.x, (_Float16)a0.y, (_Float16)a0.z, (_Float16)a0.w,
               (_Float16)a1.x, (_Float16)a1.y, (_Float16)a1.z, (_Float16)a1.w};
    *(f16_8*)&T[row * 72 + c8] = v;
    __syncthreads();
    int ntl = t >> 6, L = t & 63;
    f16_8 w;
#pragma unroll
    for (int j = 0; j < 8; j++)
      w[j] = T[((L >> 4) * 8 + j) * 72 + ntl * 16 + (L & 15)];
    *(f16_8*)&w4p[((kt * 64 + nc * 4 + ntl) * 64 + L) * 8] = w;
  } else if (b < 264) {             // W2 pack
    int q0 = (b - 256) * 256 + t;
    int L = q0 & 63, nt = (q0 >> 6) & 7, kt = q0 >> 9;
    f16_8 v;
#pragma unroll
    for (int j = 0; j < 8; j++)
      v[j] = (_Float16)W2[(kt * 32 + ((L >> 4) << 3) + j) * 128 + (nt << 4) + (L & 15)];
    *(f16_8*)&w2p[((kt * 8 + nt) * 64 + L) * 8] = v;
  } else if (b == 264) {            // GN quadform consts
    if (t < 128) {
      float a0 = W1[t], a1 = W1[128 + t], a2 = W1[256 + t], bb = b1[t];
      float p[14] = {a0, a1, a2, bb,
                     a0 * a0, 2.f * a0 * a1, 2.f * a0 * a2,
                     a1 * a1, 2.f * a1 * a2, a2 * a2,
                     2.f * bb * a0, 2.f * bb * a1, 2.f * bb * a2, bb * bb};
#pragma unroll
      for (int m = 1; m < 16; m <<= 1)
#pragma unroll
        for (int k = 0; k < 14; k++) p[k] += __shfl_xor(p[k], m, 64);
      if ((t & 15) == 0) {
        int gg = t >> 4;
#pragma unroll
        for (int k = 0; k < 4; k++) gc[gg * 16 + k] = p[k] * 0.0625f;
#pragma unroll
        for (int k = 4; k < 14; k++) gc[gg * 16 + k] = p[k];
      }
    }
  } else {                          // W3 pack: 4kt x 32nt x 64L
    int q1 = (b - 265) * 256 + t;
    int L = q1 & 63, nt = (q1 >> 6) & 31, kt = q1 >> 11;
    f16_8 v;
#pragma unroll
    for (int j = 0; j < 8; j++)
      v[j] = (_Float16)W3[(kt * 32 + ((L >> 4) << 3) + j) * 512 + (nt << 4) + (L & 15)];
    *(f16_8*)&w3p[((kt * 32 + nt) * 64 + L) * 8] = v;
  }
}

// K1: per-graph node net + max pool. Stats fp32 quadform (unchanged); channel
// affine chain now PACKED fp16 (v_pk_fma/mul/max, 2 ch/instr, no final cvt):
// per-item VALU ~84 -> ~55 ops. leaky(y) = max(y, 0.2y). Params held as f16_2
// (24 VGPR vs 48). A-tile linear 256 B/row + XOR swizzle (R7).
// NOTE (R5): 4-graphs/block spilled (VGPR=64, scratch-bound) — 1 graph/block.
__global__ __launch_bounds__(256, 4) void k1_nodenet(
    const float* __restrict__ x, const float* __restrict__ roi,
    const float* __restrict__ W1, const float* __restrict__ b1,
    const float* __restrict__ gn_g, const float* __restrict__ gn_b,
    const _Float16* __restrict__ w2p, const float* __restrict__ b2,
    const float* __restrict__ gc, _Float16* __restrict__ zh) {
  __shared__ float4 xs4[NNODES];
  __shared__ _Float16 A[128 * 128];   // linear 256 B/row + XOR swizzle
  int t = threadIdx.x, g = blockIdx.x;
  int lane = t & 63, wv = t >> 6, quad = lane >> 4, l16 = lane & 15;

  int o = t & 15;
  int gq = o >> 1;
  float gcv[14];
#pragma unroll
  for (int j = 0; j < 14; j++) gcv[j] = gc[gq * 16 + j];

  // packed fp16 per-channel params (2 channels per register)
  f16_2 qw0[4], qw1[4], qw2[4], qb[4], qg[4], qbe[4];
#pragma unroll
  for (int j = 0; j < 4; j++) {
    int c = o * 8 + j * 2;
    qw0[j] = (f16_2){(_Float16)W1[c],        (_Float16)W1[c + 1]};
    qw1[j] = (f16_2){(_Float16)W1[128 + c],  (_Float16)W1[128 + c + 1]};
    qw2[j] = (f16_2){(_Float16)W1[256 + c],  (_Float16)W1[256 + c + 1]};
    qb[j]  = (f16_2){(_Float16)b1[c],        (_Float16)b1[c + 1]};
    qg[j]  = (f16_2){(_Float16)gn_g[c],      (_Float16)gn_g[c + 1]};
    qbe[j] = (f16_2){(_Float16)gn_b[c],      (_Float16)gn_b[c + 1]};
  }

  f16_8 bh[4][2];
#pragma unroll
  for (int kt = 0; kt < 4; kt++)
#pragma unroll
    for (int ni = 0; ni < 2; ni++)
      bh[kt][ni] = *(const f16_8*)&w2p[((kt * 8 + wv * 2 + ni) * 64 + lane) * 8];

  for (int i = t; i < NNODES * 3; i += 256) {
    float v = x[g * (NNODES * 3) + i] * roi[i];
    ((float*)xs4)[(i / 3) * 4 + (i % 3)] = v;
  }
  __syncthreads();

  const f16_2 c02 = (f16_2){(_Float16)0.2f, (_Float16)0.2f};
  for (int it = t; it < 2048; it += 256) {
    int n = it >> 4;
    f16_8 hv;
    if (n < NNODES) {
      float4 xv = xs4[n];
      float mu = fmaf(xv.z, gcv[2], fmaf(xv.y, gcv[1], fmaf(xv.x, gcv[0], gcv[3])));
      float qf = fmaf(xv.z, gcv[12], fmaf(xv.y, gcv[11], fmaf(xv.x, gcv[10], gcv[13])));
      float u0 = fmaf(xv.z, gcv[6], fmaf(xv.y, gcv[5], xv.x * gcv[4]));
      qf = fmaf(xv.x, u0, qf);
      float u1 = fmaf(xv.z, gcv[8], xv.y * gcv[7]);
      qf = fmaf(xv.y, u1, qf);
      qf = fmaf(xv.z * xv.z, gcv[9], qf);
      float var = fmaxf(qf * 0.0625f - mu * mu, 0.0f);
      float ia = rsqrtf(var + 1e-5f);
      float ib = -mu * ia;
      _Float16 xh0 = (_Float16)xv.x, xh1 = (_Float16)xv.y, xh2 = (_Float16)xv.z;
      _Float16 iah = (_Float16)ia, ibh = (_Float16)ib;
      f16_2 vx = (f16_2){xh0, xh0};
      f16_2 vy = (f16_2){xh1, xh1};
      f16_2 vz = (f16_2){xh2, xh2};
      f16_2 via = (f16_2){iah, iah};
      f16_2 vib = (f16_2){ibh, ibh};
#pragma unroll
      for (int j = 0; j < 4; j++) {
        f16_2 h = vx * qw0[j] + qb[j];       // v_pk_fma_f16
        h = vy * qw1[j] + h;
        h = vz * qw2[j] + h;
        f16_2 yv = h * via + vib;            // GN normalize
        yv = yv * qg[j] + qbe[j];            // GN affine
        f16_2 y2 = yv * c02;
        yv = __builtin_elementwise_max(yv, y2);  // leaky: max(y, 0.2y)
        hv[j * 2]     = yv[0];
        hv[j * 2 + 1] = yv[1];
      }
    } else {
#pragma unroll
      for (int j = 0; j < 8; j++) hv[j] = (_Float16)0.f;
    }
    // swizzled store: row n, 16-B slot o, slot ^= (n&7)
    *(f16_8*)((char*)A + n * 256 + ((o * 16) ^ ((n & 7) << 4))) = hv;
  }
  __syncthreads();

  f32x4 acc[2][8];
#pragma unroll
  for (int a = 0; a < 2; a++)
#pragma unroll
    for (int m = 0; m < 8; m++) acc[a][m] = (f32x4){0.f, 0.f, 0.f, 0.f};

  int sx = (l16 & 7) << 4;   // (row&7)<<4 for row = mt*16 + l16
#pragma unroll
  for (int kt = 0; kt < 4; kt++) {
    f16_8 ah[8];
#pragma unroll
    for (int mt = 0; mt < 8; mt++)
      ah[mt] = *(const f16_8*)((const char*)A + (mt * 16 + l16) * 256 +
                               ((kt * 64 + quad * 16) ^ sx));
#pragma unroll
    for (int ni = 0; ni < 2; ni++)
#pragma unroll
      for (int mt = 0; mt < 8; mt++)
        acc[ni][mt] = __builtin_amdgcn_mfma_f32_16x16x32_f16(ah[mt], bh[kt][ni], acc[ni][mt], 0, 0, 0);
  }

#pragma unroll
  for (int ni = 0; ni < 2; ni++) {
    int nt = wv * 2 + ni;
    float m = -3.4e38f;
#pragma unroll
    for (int mt = 0; mt < 8; mt++)
#pragma unroll
      for (int r = 0; r < 4; r++) {
        int row = mt * 16 + quad * 4 + r;
        if (row < NNODES) m = fmaxf(m, acc[ni][mt][r]);
      }
    m = fmaxf(m, __shfl_xor(m, 16, 64));
    m = fmaxf(m, __shfl_xor(m, 32, 64));
    if (quad == 0) {
      int col = nt * 16 + l16;
      zh[g * 128 + col] = (_Float16)(m + b2[col]);
    }
  }
}

// K2: p = zh @ W3 + b3 via MFMA -> fp16 ph; fused deterministic BN partials.
// 512 blocks = 256 row-blocks x 2 col-halves; block = 16 rows x 256 cols,
// 4 waves, wave owns 64 cols (4 ni). A-frags loaded DIRECTLY from global zh
// (1 MB, L2-resident; no LDS staging). 16 MFMA/wave. Partials: fixed r-loop +
// fixed xor-16/32 tree -> deterministic; psum layout unchanged (k3 untouched).
__global__ __launch_bounds__(256) void k2_proj(
    const _Float16* __restrict__ zh, const _Float16* __restrict__ w3p,
    const float* __restrict__ b3, _Float16* __restrict__ ph,
    float* __restrict__ psum, float* __restrict__ psq) {
  int t = threadIdx.x;
  int rb = blockIdx.x >> 1, cb = blockIdx.x & 1;
  int lane = t & 63, w = t >> 6, quad = lane >> 4, l16 = lane & 15;

  f16_8 bf[4][4];
#pragma unroll
  for (int kt = 0; kt < 4; kt++)
#pragma unroll
    for (int ni = 0; ni < 4; ni++)
      bf[kt][ni] = *(const f16_8*)&w3p[((kt * 32 + cb * 16 + w * 4 + ni) * 64 + lane) * 8];

  const _Float16* za = &zh[(rb * 16 + l16) * 128 + quad * 8];
  f32x4 acc[4];
#pragma unroll
  for (int ni = 0; ni < 4; ni++) acc[ni] = (f32x4){0.f, 0.f, 0.f, 0.f};
#pragma unroll
  for (int kt = 0; kt < 4; kt++) {
    f16_8 af = *(const f16_8*)&za[kt * 32];
#pragma unroll
    for (int ni = 0; ni < 4; ni++)
      acc[ni] = __builtin_amdgcn_mfma_f32_16x16x32_f16(af, bf[kt][ni], acc[ni], 0, 0, 0);
  }

#pragma unroll
  for (int ni = 0; ni < 4; ni++) {
    int col = cb * 256 + w * 64 + ni * 16 + l16;
    float bv = b3[col];
    float sx = 0.f, qx = 0.f;
#pragma unroll
    for (int r = 0; r < 4; r++) {
      float v = acc[ni][r] + bv;
      ph[(rb * 16 + quad * 4 + r) * 512 + col] = (_Float16)v;
      sx += v;
      qx = fmaf(v, v, qx);
    }
    sx += __shfl_xor(sx, 16, 64);
    sx += __shfl_xor(sx, 32, 64);
    qx += __shfl_xor(qx, 16, 64);
    qx += __shfl_xor(qx, 32, 64);
    if (quad == 0) {
      psum[rb * 512 + col] = sx;
      psq[rb * 512 + col] = qx;
    }
  }
}

// K3: parallel reduce of 256 partials -> BN scale a, shift d.
// 64 blocks x 8 cols; 32 lanes/col each summing 8 partials, butterfly combine.
// Fixed partition + fixed tree order -> deterministic.
__global__ __launch_bounds__(256) void k3_stats(
    const float* __restrict__ psum, const float* __restrict__ psq,
    const float* __restrict__ bn_g, const float* __restrict__ bn_b,
    float* __restrict__ sa, float* __restrict__ sd) {
  int t = threadIdx.x;
  int c = blockIdx.x * 8 + (t >> 5);
  int l = t & 31;
  float s = 0.f, q = 0.f;
#pragma unroll
  for (int i = 0; i < 8; i++) {
    int b = l + i * 32;
    s += psum[b * 512 + c];
    q += psq[b * 512 + c];
  }
#pragma unroll
  for (int m = 1; m < 32; m <<= 1) {
    s += __shfl_xor(s, m, 64);
    q += __shfl_xor(q, m, 64);
  }
  if (l == 0) {
    float mu = s * (1.0f / 4096.0f);
    float var = fmaxf(q * (1.0f / 4096.0f) - mu * mu, 0.0f);
    float sc = bn_g[c] * rsqrtf(var + 1e-5f);
    sa[c] = sc;
    sd[c] = bn_b[c] - mu * sc;
  }
}

// K4: fused p@W4 + b4 + L2-normalize. 128 blocks x 32 rows x FULL 1024 cols
// (512 threads; wave w owns cols [128w,128w+128), 2 row-tiles). A =
// relu(ph*sa+sd) staged once in LDS ([kt][32 rows][40] fp16 = 40 KB), K-loop
// has ZERO barriers: B streamed from L2 via double-buffered register prefetch
// (static indices). Row sumsq reduced in-reg + LDS; out written once,
// normalized. Fixed reduce order -> deterministic.
__global__ __launch_bounds__(512) void k4_gemm(
    const _Float16* __restrict__ ph, const float* __restrict__ sa,
    const float* __restrict__ sd, const _Float16* __restrict__ w4p,
    const float* __restrict__ b4, float* __restrict__ out) {
  __shared__ _Float16 A[16 * 32 * 40];   // [kt][row(32)][40] : 40 KB
  __shared__ float sas[512], sds[512];
  __shared__ float rowsq[8][32];
  __shared__ float rinv[32];
  int t = threadIdx.x;
  int rb = blockIdx.x;                   // 32 rows per block
  int lane = t & 63, w = t >> 6, quad = lane >> 4, l16 = lane & 15;

  sas[t] = sa[t];
  sds[t] = sd[t];

  // stage loads: 32 rows x 64 f16_8-segs = 2048 slots, 4 per thread, coalesced
  f16_8 pv[4];
#pragma unroll
  for (int p = 0; p < 4; p++) {
    int idx = t + p * 512;
    int row = idx >> 6, seg = idx & 63;
    pv[p] = *(const f16_8*)&ph[(rb * 32 + row) * 512 + seg * 8];
  }
  int nt0 = w * 8;
  f16_8 bf0[8], bf1[8];
#pragma unroll
  for (int ni = 0; ni < 8; ni++)
    bf0[ni] = *(const f16_8*)&w4p[((nt0 + ni) * 64 + lane) * 8];
  __syncthreads();   // sas/sds ready

#pragma unroll
  for (int p = 0; p < 4; p++) {
    int idx = t + p * 512;
    int row = idx >> 6, seg = idx & 63;
    int kt = seg >> 2, c8 = seg & 3;
    f16_8 v;
#pragma unroll
    for (int j = 0; j < 8; j++) {
      float vv = fmaf((float)pv[p][j], sas[seg * 8 + j], sds[seg * 8 + j]);
      v[j] = (_Float16)fmaxf(vv, 0.f);
    }
    *(f16_8*)&A[(kt * 32 + row) * 40 + c8 * 8] = v;
  }
  __syncthreads();   // A ready; no more barriers until epilogue

  f32x4 acc[2][8];
#pragma unroll
  for (int mt = 0; mt < 2; mt++)
#pragma unroll
    for (int ni = 0; ni < 8; ni++) acc[mt][ni] = (f32x4){0.f, 0.f, 0.f, 0.f};

#pragma unroll
  for (int kt2 = 0; kt2 < 8; kt2++) {
    const int ktA = kt2 * 2, ktB = kt2 * 2 + 1;
#pragma unroll
    for (int ni = 0; ni < 8; ni++)
      bf1[ni] = *(const f16_8*)&w4p[(((ktA + 1) * 64 + nt0 + ni) * 64 + lane) * 8];
    f16_8 afA0 = *(const f16_8*)&A[(ktA * 32 + l16) * 40 + quad * 8];
    f16_8 afA1 = *(const f16_8*)&A[(ktA * 32 + 16 + l16) * 40 + quad * 8];
#pragma unroll
    for (int ni = 0; ni < 8; ni++)
      acc[0][ni] = __builtin_amdgcn_mfma_f32_16x16x32_f16(afA0, bf0[ni], acc[0][ni], 0, 0, 0);
#pragma unroll
    for (int ni = 0; ni < 8; ni++)
      acc[1][ni] = __builtin_amdgcn_mfma_f32_16x16x32_f16(afA1, bf0[ni], acc[1][ni], 0, 0, 0);
    if (kt2 < 7) {
#pragma unroll
      for (int ni = 0; ni < 8; ni++)
        bf0[ni] = *(const f16_8*)&w4p[(((ktB + 1) * 64 + nt0 + ni) * 64 + lane) * 8];
    }
    f16_8 afB0 = *(const f16_8*)&A[(ktB * 32 + l16) * 40 + quad * 8];
    f16_8 afB1 = *(const f16_8*)&A[(ktB * 32 + 16 + l16) * 40 + quad * 8];
#pragma unroll
    for (int ni = 0; ni < 8; ni++)
      acc[0][ni] = __builtin_amdgcn_mfma_f32_16x16x32_f16(afB0, bf1[ni], acc[0][ni], 0, 0, 0);
#pragma unroll
    for (int ni = 0; ni < 8; ni++)
      acc[1][ni] = __builtin_amdgcn_mfma_f32_16x16x32_f16(afB1, bf1[ni], acc[1][ni], 0, 0, 0);
  }

  // epilogue: +b4, row sumsq for 32 rows (rows mt*16+quad*4+r), wave-local
  // reduce over l16, then cross-wave fixed-order sum in LDS.
  float rsq[2][4];
#pragma unroll
  for (int mt = 0; mt < 2; mt++)
#pragma unroll
    for (int r = 0; r < 4; r++) rsq[mt][r] = 0.f;
#pragma unroll
  for (int ni = 0; ni < 8; ni++) {
    float bv = b4[w * 128 + ni * 16 + l16];
#pragma unroll
    for (int mt = 0; mt < 2; mt++)
#pragma unroll
      for (int r = 0; r < 4; r++) {
        float v = acc[mt][ni][r] + bv;
        acc[mt][ni][r] = v;
        rsq[mt][r] = fmaf(v, v, rsq[mt][r]);
      }
  }
#pragma unroll
  for (int m = 1; m < 16; m <<= 1)
#pragma unroll
    for (int mt = 0; mt < 2; mt++)
#pragma unroll
      for (int r = 0; r < 4; r++) rsq[mt][r] += __shfl_xor(rsq[mt][r], m, 64);
  if (l16 == 0)
#pragma unroll
    for (int mt = 0; mt < 2; mt++)
#pragma unroll
      for (int r = 0; r < 4; r++)
        rowsq[w][mt * 16 + quad * 4 + r] = rsq[mt][r];
  __syncthreads();
  if (t < 32) {
    float s = 0.f;
#pragma unroll
    for (int ww = 0; ww < 8; ww++) s += rowsq[ww][t];   // fixed order
    rinv[t] = 1.0f / fmaxf(sqrtf(s), 1e-12f);
  }
  __syncthreads();
#pragma unroll
  for (int mt = 0; mt < 2; mt++)
#pragma unroll
    for (int r = 0; r < 4; r++) {
      float inv = rinv[mt * 16 + quad * 4 + r];
      int obase = (rb * 32 + mt * 16 + quad * 4 + r) * 1024 + w * 128 + l16;
#pragma unroll
      for (int ni = 0; ni < 8; ni++)
        out[obase + ni * 16] = acc[mt][ni][r] * inv;
    }
}

extern "C" void kernel_launch(void* const* d_in, const int* in_sizes, int n_in,
                              void* d_out, int out_size, void* d_ws, size_t ws_size,
                              hipStream_t stream) {
  const float* x   = (const float*)d_in[0];
  const float* roi = (const float*)d_in[1];
  const float* W1  = (const float*)d_in[2];
  const float* b1  = (const float*)d_in[3];
  const float* gng = (const float*)d_in[4];
  const float* gnb = (const float*)d_in[5];
  const float* W2  = (const float*)d_in[6];
  const float* b2  = (const float*)d_in[7];
  const float* W3  = (const float*)d_in[8];
  const float* b3  = (const float*)d_in[9];
  const float* bng = (const float*)d_in[10];
  const float* bnb = (const float*)d_in[11];
  const float* W4  = (const float*)d_in[12];
  const float* b4  = (const float*)d_in[13];
  float* out = (float*)d_out;

  char* ws = (char*)d_ws;
  _Float16* zh   = (_Float16*)(ws + ZH_OFF);
  _Float16* w3p  = (_Float16*)(ws + W3P_OFF);
  _Float16* ph   = (_Float16*)(ws + PH_OFF);
  float*    psum = (float*)(ws + PSUM_OFF);
  float*    psq  = (float*)(ws + PSQ_OFF);
  float*    gc   = (float*)(ws + GC_OFF);
  float*    sa   = (float*)(ws + SA_OFF);
  float*    sd   = (float*)(ws + SD_OFF);
  _Float16* w2p  = (_Float16*)(ws + W2P_OFF);
  _Float16* w4p  = (_Float16*)(ws + W4P_OFF);

  k0_prep<<<297, 256, 0, stream>>>(W2, W4, W1, b1, W3, w2p, w4p, w3p, gc);
  k1_nodenet<<<NGRAPH, 256, 0, stream>>>(x, roi, W1, b1, gng, gnb, w2p, b2, gc, zh);
  k2_proj<<<512, 256, 0, stream>>>(zh, w3p, b3, ph, psum, psq);
  k3_stats<<<64, 256, 0, stream>>>(psum, psq, bng, bnb, sa, sd);
  k4_gemm<<<128, 512, 0, stream>>>(ph, sa, sd, w4p, b4, out);
}